// Round 7
// baseline (92.879 us; speedup 1.0000x reference)
//
#include <hip/hip_runtime.h>

#define NBODY 8192
#define BLOCK 256
#define IPT 4                       // i-bodies per thread
#define ITILE (BLOCK * IPT)         // 1024
#define NITILES (NBODY / ITILE)     // 8
#define SLABS 128                   // j-slabs
#define JCHUNK (NBODY / SLABS)      // 64 j-bodies per slab
#define PHASE 16                    // j-bodies register-hoisted per phase
#define NPHASE (JCHUNK / PHASE)     // 4
#define NF (NBODY * 3)              // 24576 output floats
#define SOFT2 1.0e-4f               // 0.01^2

// Issue-cost fit across R0/R3/R4 (three geometries, one constant): v_rsq_f32
// occupies the issue port ~55-60 cy/wave64 (~30x a full-rate op) -> rsq was
// ~67% of force-kernel time and explains why occupancy/ILP/DS/packed-math all
// came back null. This round replaces v_rsq with a full-rate-only software
// rsqrt: bit-trick seed + 3 Newton iterations (12 ops, converges to fp32
// rounding floor since err 0.034 -> 1.8e-3 -> 4.6e-6 -> <1e-7). Per pair:
// 12 full + 1 trans (24+~57 cy) -> 24 full + 0 trans (48 cy).
__device__ __forceinline__ float fast_rsqrt(float q) {
  float y = __int_as_float(0x5f375a86 - (__float_as_int(q) >> 1));
  const float h = 0.5f * q;
  float t;
  t = h * y; y = y * fmaf(-t, y, 1.5f);
  t = h * y; y = y * fmaf(-t, y, 1.5f);
  t = h * y; y = y * fmaf(-t, y, 1.5f);
  return y;
}

// R4 structure unchanged (best measured: phase-hoisted register compute,
// IPT=4, SoA partials + reduce). Single variable this round: rsq -> NR.
__global__ __launch_bounds__(BLOCK, 4) void force_kernel(
    const float* __restrict__ pos, const float* __restrict__ mass,
    float* __restrict__ part) {
  __shared__ float4 tile[JCHUNK];

  const int t = threadIdx.x;
  const int j0 = blockIdx.y * JCHUNK;
  if (t < JCHUNK) {
    const int j = j0 + t;
    tile[t] =
        make_float4(pos[j * 3 + 0], pos[j * 3 + 1], pos[j * 3 + 2], mass[j]);
  }

  const int ib = blockIdx.x * ITILE + t;  // i-bodies: ib + p*BLOCK
  float xi[IPT], yi[IPT], zi[IPT];
  float ax[IPT], ay[IPT], az[IPT];
#pragma unroll
  for (int p = 0; p < IPT; ++p) {
    const int i = ib + p * BLOCK;
    xi[p] = pos[i * 3 + 0];
    yi[p] = pos[i * 3 + 1];
    zi[p] = pos[i * 3 + 2];
    ax[p] = 0.f;
    ay[p] = 0.f;
    az[p] = 0.f;
  }

  __syncthreads();

  for (int c = 0; c < NPHASE; ++c) {
    // Burst-hoist one phase of j-bodies into registers (64 VGPR); 16
    // independent ds_read_b128, single wait (R4: -3us vs in-loop broadcast).
    float4 jt[PHASE];
#pragma unroll
    for (int u = 0; u < PHASE; ++u) jt[u] = tile[c * PHASE + u];

    // Pure-register, pure-full-rate compute: 16 j x 4 i = 64 pairs.
#pragma unroll
    for (int u = 0; u < PHASE; ++u) {
#pragma unroll
      for (int p = 0; p < IPT; ++p) {
        float dx = jt[u].x - xi[p];
        float dy = jt[u].y - yi[p];
        float dz = jt[u].z - zi[p];
        float r2 = fmaf(dx, dx, fmaf(dy, dy, fmaf(dz, dz, SOFT2)));
        float y = fast_rsqrt(r2);               // 12 full-rate ops, no trans
        float w = jt[u].w * (y * (y * y));      // m_j * r^-3
        ax[p] = fmaf(w, dx, ax[p]);
        ay[p] = fmaf(w, dy, ay[p]);
        az[p] = fmaf(w, dz, az[p]);
      }
    }
  }

  // SoA partials [slab][comp][body]: fully coalesced stores, no contention.
  float* __restrict__ dst = part + (size_t)blockIdx.y * NF;
#pragma unroll
  for (int p = 0; p < IPT; ++p) {
    const int i = ib + p * BLOCK;
    dst[0 * NBODY + i] = ax[p];
    dst[1 * NBODY + i] = ay[p];
    dst[2 * NBODY + i] = az[p];
  }
}

// grid (96, 4): block (bx, g) sums slabs [g*32, g*32+32), one 4-way-contended
// atomicAdd per output element. ~2-3us (R4-proven).
__global__ __launch_bounds__(BLOCK) void reduce_kernel(
    const float* __restrict__ part, float* __restrict__ out) {
  const int idx = blockIdx.x * BLOCK + threadIdx.x;  // SoA index < NF
  const int c = idx >> 13;          // component (idx / NBODY)
  const int b = idx & (NBODY - 1);  // body
  const int sl0 = blockIdx.y * (SLABS / 4);
  float s0 = 0.f, s1 = 0.f, s2 = 0.f, s3 = 0.f;
#pragma unroll 8
  for (int sl = 0; sl < SLABS / 4; sl += 4) {
    s0 += part[(size_t)(sl0 + sl + 0) * NF + idx];
    s1 += part[(size_t)(sl0 + sl + 1) * NF + idx];
    s2 += part[(size_t)(sl0 + sl + 2) * NF + idx];
    s3 += part[(size_t)(sl0 + sl + 3) * NF + idx];
  }
  atomicAdd(&out[b * 3 + c], (s0 + s1) + (s2 + s3));
}

extern "C" void kernel_launch(void* const* d_in, const int* in_sizes, int n_in,
                              void* d_out, int out_size, void* d_ws,
                              size_t ws_size, hipStream_t stream) {
  const float* pos = (const float*)d_in[0];
  const float* mass = (const float*)d_in[1];
  float* out = (float*)d_out;
  float* part = (float*)d_ws;  // 128 * 24576 * 4 B = 12.6 MB

  // d_out is re-poisoned before each launch; atomics in reduce need zeros.
  hipMemsetAsync(d_out, 0, (size_t)out_size * sizeof(float), stream);

  force_kernel<<<dim3(NITILES, SLABS), BLOCK, 0, stream>>>(pos, mass, part);
  reduce_kernel<<<dim3(NF / BLOCK, 4), BLOCK, 0, stream>>>(part, out);
}